// Round 1
// 292.408 us; speedup vs baseline: 1.0138x; 1.0138x over previous
//
#include <hip/hip_runtime.h>
#include <math.h>

// HBV model RHS: elementwise over B=2,000,000 rows.
// Inputs (dict order):
//   d_in[0] = y            (B,5)   float32   in_sizes[0] = 5B
//   d_in[1] = theta        (14,)   float32
//   d_in[2] = climate_data (8,B,3) float32
//   d_in[3] = delta_t      scalar  float32
//   d_in[4] = t            scalar  int32
// Output: concat[ dS (B,5), fluxes (B,12) ] float32, out_size = 17B
//
// R1: all global traffic staged through LDS so every global access is a
//     coalesced float4. Row strides 5/3/5/12 live only in LDS.
// R2 (this round): pure-streaming kernel, 200 MB touch-once traffic.
//     (a) __builtin_nontemporal_load/store on every global float4 — no
//         L2/L3 allocation for data we never revisit.
//     (b) Full-tile fast path with compile-time trip counts: explicit
//         global->reg staging (all loads issued back-to-back for MLP),
//         then reg->LDS, barrier, compute, barrier, nt stores.
//     Generic loop path kept only for the single partial tail block.

#define BLOCK 256

typedef float f4 __attribute__((ext_vector_type(4)));

__global__ __launch_bounds__(BLOCK) void hbv_rhs_kernel(
    const float* __restrict__ y,
    const float* __restrict__ theta,
    const float* __restrict__ climate,
    const float* __restrict__ dt_ptr,
    const int* __restrict__ t_ptr,
    float* __restrict__ dS,
    float* __restrict__ fluxes,
    int B)
{
    __shared__ float lds_y[BLOCK * 5];
    __shared__ float lds_c[BLOCK * 3];
    __shared__ float lds_d[BLOCK * 5];
    __shared__ float lds_f[BLOCK * 12];

    const int tid  = threadIdx.x;
    const int base = blockIdx.x * BLOCK;
    const int nrows = min(BLOCK, B - base);
    const bool full = (nrows == BLOCK);

    const float dt = dt_ptr[0];
    const int   t  = t_ptr[0];
    const float* __restrict__ ct = climate + (size_t)t * (size_t)B * 3u;

    // ---- Phase 1: coalesced global -> LDS ----
    const float* __restrict__ yb = y  + (size_t)base * 5u;   // 5120B-aligned per block
    const float* __restrict__ cb = ct + (size_t)base * 3u;   // 3072B-aligned per block

    if (full) {
        // Full tile: ny4 = 320 f4, nc4 = 192 f4 — constant trip counts.
        // Issue all nt loads first (max memory-level parallelism), then LDS writes.
        const f4* __restrict__ yb4 = (const f4*)yb;
        const f4* __restrict__ cb4 = (const f4*)cb;
        f4 ry0 = __builtin_nontemporal_load(yb4 + tid);
        f4 ry1, rc0;
        const bool hy1 = (tid < (BLOCK * 5 / 4 - BLOCK));  // 64 lanes
        const bool hc0 = (tid < (BLOCK * 3 / 4));          // 192 lanes
        if (hy1) ry1 = __builtin_nontemporal_load(yb4 + BLOCK + tid);
        if (hc0) rc0 = __builtin_nontemporal_load(cb4 + tid);
        ((f4*)lds_y)[tid] = ry0;
        if (hy1) ((f4*)lds_y)[BLOCK + tid] = ry1;
        if (hc0) ((f4*)lds_c)[tid] = rc0;
    } else {
        const int ny = nrows * 5, nc = nrows * 3;
        const int ny4 = ny >> 2, nc4 = nc >> 2;
        for (int k = tid; k < ny4; k += BLOCK)
            ((f4*)lds_y)[k] = ((const f4*)yb)[k];
        for (int k = ny4 * 4 + tid; k < ny; k += BLOCK)
            lds_y[k] = yb[k];
        for (int k = tid; k < nc4; k += BLOCK)
            ((f4*)lds_c)[k] = ((const f4*)cb)[k];
        for (int k = nc4 * 4 + tid; k < nc; k += BLOCK)
            lds_c[k] = cb[k];
    }

    // Broadcast scalars (uniform, s_load path) — overlaps with load latency.
    const float tt    = theta[0];
    const float tti   = theta[1];
    const float ttm   = theta[2];
    const float cfr   = theta[3];
    const float cfmax = theta[4];
    const float whc   = theta[5];
    const float cflux = theta[6];
    const float fc    = theta[7];
    const float lp    = theta[8];
    const float beta  = theta[9];
    const float k0    = theta[10];
    const float alpha = theta[11];
    const float perc  = theta[12];
    const float k1    = theta[13];

    __syncthreads();

    // ---- Phase 2: per-row compute from/to LDS ----
    if (tid < nrows) {
        const float S1 = lds_y[tid * 5 + 0];
        const float S2 = lds_y[tid * 5 + 1];
        const float S3 = lds_y[tid * 5 + 2];
        const float S4 = lds_y[tid * 5 + 3];
        const float S5 = lds_y[tid * 5 + 4];
        const float P  = lds_c[tid * 3 + 0];
        const float Ep = lds_c[tid * 3 + 1];
        const float T  = lds_c[tid * 3 + 2];

        const float zero = 0.0f;
        const float flux_sf   = fminf(P, fmaxf(zero, P * (tt + 0.5f * tti - T) / tti));
        const float flux_refr = fmaxf(fminf(cfr * cfmax * (ttm - T), S2 / dt), zero);
        const float flux_melt = fmaxf(fminf(cfmax * (T - ttm), S1 / dt), zero);
        const float flux_rf   = fminf(P, fmaxf(zero, P * (T - (tt - 0.5f * tti)) / tti));

        const float r = 0.01f, e = 5.0f;
        const float Smax_raw = whc * S1;
        const float Smax     = fmaxf(Smax_raw, zero);
        const float logistic = 1.0f / (1.0f + expf((S2 - Smax + r * e * Smax) / fmaxf(r, r * Smax)));
        const float flux_in  = (flux_rf + flux_melt) * (1.0f - logistic);
        const float flux_se  = fmaxf((S2 - Smax_raw) / dt, zero);
        const float flux_cf  = fminf(cflux * (1.0f - S3 / fc), S4 / dt);
        const float flux_ea  = fminf(fminf(S3 / (lp * fc) * Ep, Ep), S3 / dt);
        const float flux_r   = (flux_in + flux_se) * powf(fmaxf(S3, zero) / fc, beta);
        const float flux_q0  = fminf(k0 * powf(fmaxf(S4, zero), 1.0f + alpha), fmaxf(S4 / dt, zero));
        const float flux_perc = fminf(perc, S4 / dt);
        const float flux_q1  = k1 * S5;

        lds_d[tid * 5 + 0] = flux_sf + flux_refr - flux_melt;
        lds_d[tid * 5 + 1] = flux_rf + flux_melt - flux_refr - flux_in - flux_se;
        lds_d[tid * 5 + 2] = flux_in + flux_se + flux_cf - flux_ea - flux_r;
        lds_d[tid * 5 + 3] = flux_r - flux_cf - flux_q0 - flux_perc;
        lds_d[tid * 5 + 4] = flux_perc - flux_q1;

        f4* f4p = (f4*)(lds_f + tid * 12);  // 48B stride, 16B aligned
        f4p[0] = (f4){flux_sf, flux_refr, flux_melt, flux_rf};
        f4p[1] = (f4){flux_in, flux_se, flux_cf, flux_ea};
        f4p[2] = (f4){flux_r, flux_q0, flux_perc, flux_q1};
    }

    __syncthreads();

    // ---- Phase 3: coalesced LDS -> global (nt stores) ----
    float* __restrict__ db = dS     + (size_t)base * 5u;   // 5120B-aligned
    float* __restrict__ fb = fluxes + (size_t)base * 12u;  // 12288B-aligned

    if (full) {
        f4* __restrict__ db4 = (f4*)db;
        f4* __restrict__ fb4 = (f4*)fb;
        // nd4 = 320 f4, nf4 = 768 f4 — constant trip counts.
        __builtin_nontemporal_store(((const f4*)lds_d)[tid], db4 + tid);
        if (tid < (BLOCK * 5 / 4 - BLOCK))  // 64 lanes
            __builtin_nontemporal_store(((const f4*)lds_d)[BLOCK + tid], db4 + BLOCK + tid);
#pragma unroll
        for (int k = 0; k < 3; ++k)
            __builtin_nontemporal_store(((const f4*)lds_f)[tid + k * BLOCK], fb4 + tid + k * BLOCK);
    } else {
        const int nd = nrows * 5, nf = nrows * 12;
        const int nd4 = nd >> 2, nf4 = nf >> 2;
        for (int k = tid; k < nd4; k += BLOCK)
            ((f4*)db)[k] = ((const f4*)lds_d)[k];
        for (int k = nd4 * 4 + tid; k < nd; k += BLOCK)
            db[k] = lds_d[k];
        for (int k = tid; k < nf4; k += BLOCK)
            ((f4*)fb)[k] = ((const f4*)lds_f)[k];
        for (int k = nf4 * 4 + tid; k < nf; k += BLOCK)
            fb[k] = lds_f[k];
    }
}

extern "C" void kernel_launch(void* const* d_in, const int* in_sizes, int n_in,
                              void* d_out, int out_size, void* d_ws, size_t ws_size,
                              hipStream_t stream) {
    const float* y       = (const float*)d_in[0];
    const float* theta   = (const float*)d_in[1];
    const float* climate = (const float*)d_in[2];
    const float* dt_ptr  = (const float*)d_in[3];
    const int*   t_ptr   = (const int*)d_in[4];

    const int B = in_sizes[0] / 5;

    float* dS     = (float*)d_out;                   // B*5
    float* fluxes = (float*)d_out + (size_t)B * 5u;  // B*12

    const int block = BLOCK;
    const int grid  = (B + block - 1) / block;
    hbv_rhs_kernel<<<grid, block, 0, stream>>>(y, theta, climate, dt_ptr, t_ptr,
                                               dS, fluxes, B);
}